// Round 6
// baseline (172.290 us; speedup 1.0000x reference)
//
#include <hip/hip_runtime.h>
#include <math.h>

#define Nq 2048
#define Bq 8
#define Kq 4
#define BKq 32
#define NL 32  // elements per lane (2048 / 64)
#define TWO_PI_D 6.283185307179586
#define PI_D 3.141592653589793
#define INV2PI_D 0.15915494309189535

// ---------------- wave helpers ----------------

__device__ __forceinline__ double wave_sum_d(double v) {
#pragma unroll
  for (int off = 1; off < 64; off <<= 1) v += __shfl_xor(v, off, 64);
  return v;
}

// Canonical GCN DPP wave64 sum (rocPRIM sequence); result broadcast via lane 63.
__device__ __forceinline__ float dpp_sum_f32(float v) {
  v += __int_as_float(__builtin_amdgcn_update_dpp(0, __float_as_int(v), 0x111, 0xf, 0xf, false));  // row_shr:1
  v += __int_as_float(__builtin_amdgcn_update_dpp(0, __float_as_int(v), 0x112, 0xf, 0xf, false));  // row_shr:2
  v += __int_as_float(__builtin_amdgcn_update_dpp(0, __float_as_int(v), 0x114, 0xf, 0xe, false));  // row_shr:4
  v += __int_as_float(__builtin_amdgcn_update_dpp(0, __float_as_int(v), 0x118, 0xf, 0xc, false));  // row_shr:8
  v += __int_as_float(__builtin_amdgcn_update_dpp(0, __float_as_int(v), 0x142, 0xa, 0xf, false));  // row_bcast:15
  v += __int_as_float(__builtin_amdgcn_update_dpp(0, __float_as_int(v), 0x143, 0xc, 0xf, false));  // row_bcast:31
  return __int_as_float(__builtin_amdgcn_readlane(__float_as_int(v), 63));
}

// wave-wide lane shifts (gfx9/CDNA DPP): dst lane i <- src lane i-1 / i+1.
// Edge lanes get 0 — always overwritten by the endpoint-row fixups below.
__device__ __forceinline__ float dpp_up1(float v) {   // == __shfl_up(v,1,64)
  return __int_as_float(__builtin_amdgcn_update_dpp(0, __float_as_int(v), 0x138, 0xf, 0xf, false));  // wave_shr:1
}
__device__ __forceinline__ float dpp_dn1(float v) {   // == __shfl_down(v,1,64)
  return __int_as_float(__builtin_amdgcn_update_dpp(0, __float_as_int(v), 0x130, 0xf, 0xf, false));  // wave_shl:1
}

__device__ __forceinline__ double lane_excl_prefix_d(double T, int lane) {
  double acc = T;
#pragma unroll
  for (int off = 1; off < 64; off <<= 1) {
    double t = __shfl_up(acc, off, 64);
    if (lane >= off) acc += t;
  }
  return acc - T;
}

__device__ __forceinline__ void fast_sincos_ph(double ph, float* sn, float* cs) {
  double k = trunc(ph * INV2PI_D);
  float phr = (float)(ph - k * TWO_PI_D);
  __sincosf(phr, sn, cs);
}

// Full matvec Ap = (coef*opedoub + diag(de)) p, with dd[e] = 6*coef + de[e]
// folded in. Endpoint rows (global 0,1,N-2,N-1) fixed up on lanes 0/63.
template <bool UNIT>
__device__ __forceinline__ void applyA(const float* p, float* Ap,
                                       const float* dd, float c, float c3,
                                       float c4, float ddu, int lane) {
  float lm1 = dpp_up1(p[NL - 1]);
  float lm2 = dpp_up1(p[NL - 2]);
  float rp1 = dpp_dn1(p[0]);
  float rp2 = dpp_dn1(p[1]);
#pragma unroll
  for (int e = 0; e < NL; ++e) {
    float m2 = (e >= 2) ? p[e - 2] : (e == 1 ? lm1 : lm2);
    float m1 = (e >= 1) ? p[e - 1] : lm1;
    float q1 = (e <= NL - 2) ? p[e + 1] : rp1;
    float q2 = (e <= NL - 3) ? p[e + 2] : (e == NL - 2 ? rp1 : rp2);
    float t1 = m2 + q2, t2 = m1 + q1;
    float u = fmaf(c, t1, -(c4 * t2));
    float d = UNIT ? ddu : dd[e];
    Ap[e] = fmaf(d, p[e], u);
  }
  if (lane == 0) {
    float d0 = (UNIT ? ddu : dd[0]) - c4;  // = 2c + de0
    Ap[0] = fmaf(d0, p[0], fmaf(c, p[2], -(c3 * p[1])));
    float d1 = UNIT ? ddu : dd[1];
    Ap[1] = fmaf(d1, p[1], -(c3 * p[0])) + fmaf(c, p[3], -(c4 * p[2]));
  }
  if (lane == 63) {
    float dm2 = UNIT ? ddu : dd[NL - 2];
    Ap[NL - 2] = fmaf(dm2, p[NL - 2], c * p[NL - 4]) -
                 fmaf(c4, p[NL - 3], c3 * p[NL - 1]);
    float dm1 = (UNIT ? ddu : dd[NL - 1]) - c4;  // = 2c + de
    Ap[NL - 1] = fmaf(dm1, p[NL - 1], c * p[NL - 3]) - c3 * p[NL - 2];
  }
}

// Wave CG (f32 state, zero barriers) on (coef*opedoub + diag(de)) z = rhs.
// de passed in dd[] (or unit diag); dd is destructively updated to 6c+de.
// In: x = x0, r = rhs. Out: x = solution.
template <bool UNIT>
__device__ __forceinline__ void cg_wave_f(float coef, float* dd, float* r,
                                          float* x, int lane) {
  const float c = coef, c3 = 3.0f * coef, c4 = 4.0f * coef;
  const float ddu = 6.0f * coef + (1.0f + 1e-6f);
  if (!UNIT) {
#pragma unroll
    for (int e = 0; e < NL; ++e) dd[e] += 6.0f * coef;
  }
  float p[NL], Ap[NL];
  applyA<UNIT>(x, Ap, dd, c, c3, c4, ddu, lane);
  float s0 = 0, s1 = 0, s2 = 0, s3 = 0;
#pragma unroll
  for (int e = 0; e < NL; ++e) {
    r[e] -= Ap[e];
    p[e] = r[e];
    float* acc = (e & 2) ? ((e & 1) ? &s3 : &s2) : ((e & 1) ? &s1 : &s0);
    *acc = fmaf(r[e], r[e], *acc);
  }
  float rsold = dpp_sum_f32((s0 + s1) + (s2 + s3));
  for (int it = 0; it < 30; ++it) {
    applyA<UNIT>(p, Ap, dd, c, c3, c4, ddu, lane);
    float d0 = 0, d1 = 0, d2 = 0, d3 = 0;
#pragma unroll
    for (int e = 0; e < NL; ++e) {
      float* acc = (e & 2) ? ((e & 1) ? &d3 : &d2) : ((e & 1) ? &d1 : &d0);
      *acc = fmaf(p[e], Ap[e], *acc);
    }
    float pap = dpp_sum_f32((d0 + d1) + (d2 + d3));
    float a = __fdividef(rsold, pap + 1e-12f);
    float t0 = 0, t1 = 0, t2 = 0, t3 = 0;
#pragma unroll
    for (int e = 0; e < NL; ++e) {
      x[e] = fmaf(a, p[e], x[e]);
      r[e] = fmaf(-a, Ap[e], r[e]);
      float* acc = (e & 2) ? ((e & 1) ? &t3 : &t2) : ((e & 1) ? &t1 : &t0);
      *acc = fmaf(r[e], r[e], *acc);
    }
    float rsnew = dpp_sum_f32((t0 + t1) + (t2 + t3));
    if (rsnew < 1e-12f) break;  // == sqrt(rsnew) < 1e-6 (monotone); == ref freeze
    float bta = __fdividef(rsnew, rsold + 1e-12f);
#pragma unroll
    for (int e = 0; e < NL; ++e) p[e] = fmaf(bta, p[e], r[e]);
    rsold = rsnew;
  }
}

__device__ __forceinline__ double blk_reduce(double v, double* sh) {
#pragma unroll
  for (int off = 32; off > 0; off >>= 1) v += __shfl_down(v, off, 64);
  int wid = threadIdx.x >> 6;
  int lane = threadIdx.x & 63;
  __syncthreads();
  if (lane == 0) sh[wid] = v;
  __syncthreads();
  double r = sh[0] + sh[1] + sh[2] + sh[3];
  __syncthreads();
  return r;
}

// ---------- mega kernel: one block per (b,k) row; wave0=X system, wave1=Y ----
__global__ __launch_bounds__(128, 1) void row_kernel(
    const float* __restrict__ s, const float* __restrict__ eIF,
    const float* __restrict__ xm, const float* __restrict__ ym,
    const float* __restrict__ sum_x, const float* __restrict__ sum_y,
    const float* __restrict__ lamuda, const float* __restrict__ init_freqs,
    const int* __restrict__ mode_mask, const float* __restrict__ alpha_p,
    const float* __restrict__ beta_p, const float* __restrict__ var_p,
    const float* __restrict__ fs_p, const int* __restrict__ iter_p,
    const float* __restrict__ fe_w1, const float* __restrict__ fe_b1,
    const float* __restrict__ fe_w2, const float* __restrict__ fe_b2,
    const float* __restrict__ pr_w1, const float* __restrict__ pr_b1,
    const float* __restrict__ pr_w2, const float* __restrict__ pr_b2,
    const float* __restrict__ pr_w3, const float* __restrict__ pr_b3,
    const float* __restrict__ iter_w_p, double* __restrict__ hdr,
    float* __restrict__ out_eIF, float* __restrict__ out_xm,
    float* __restrict__ out_ym, float* __restrict__ cx_w,
    float* __restrict__ cy_w, float* __restrict__ out_scal) {
  __shared__ double sh_avg[Bq];
  __shared__ double sh_h1[Bq][32];
  __shared__ double sh_z[Bq][18];
  __shared__ double sh_z1[Bq][64];
  __shared__ double sh_z2[Bq][32];
  __shared__ double sh_res[Bq][2];
  __shared__ double sh_hdr[6];
  __shared__ float sh_xs[Nq], sh_ys[Nq];

  const int tid = threadIdx.x;
  const int wv = tid >> 6, lane = tid & 63;
  const int row = blockIdx.x, b = row >> 2;
  const int bb = b * Nq, base = row * Nq;

  // ---- hyperparameter MLP (redundant per block, f64 deterministic) ----
  double alpha = (double)alpha_p[0], beta = (double)beta_p[0];
  double iterv = (double)iter_p[0];
  if (tid < Bq) {
    double avg = 0.0;
#pragma unroll
    for (int k = 0; k < Kq; ++k) avg += (double)init_freqs[tid * Kq + k];
    sh_avg[tid] = avg * (1.0 / Kq);
  }
  __syncthreads();
  for (int n = tid; n < 256; n += 128) {
    int b2 = n >> 5, j = n & 31;
    double v = (double)fe_w1[j] * sh_avg[b2] + (double)fe_b1[j];
    sh_h1[b2][j] = v > 0.0 ? v : 0.0;
  }
  __syncthreads();
  {
    int b2 = tid >> 4, j = tid & 15;
    double acc = (double)fe_b2[j];
    for (int i = 0; i < 32; ++i) acc += (double)fe_w2[j * 32 + i] * sh_h1[b2][i];
    sh_z[b2][j] = acc > 0.0 ? acc : 0.0;
  }
  if (tid < Bq) {
    sh_z[tid][16] = alpha;
    sh_z[tid][17] = beta;
  }
  __syncthreads();
  for (int n = tid; n < 512; n += 128) {
    int b2 = n >> 6, j = n & 63;
    double acc = (double)pr_b1[j];
    for (int i = 0; i < 18; ++i) acc += (double)pr_w1[j * 18 + i] * sh_z[b2][i];
    sh_z1[b2][j] = acc > 0.0 ? acc : 0.0;
  }
  __syncthreads();
  for (int n = tid; n < 256; n += 128) {
    int b2 = n >> 5, j = n & 31;
    double acc = (double)pr_b2[j];
    for (int i = 0; i < 64; ++i) acc += (double)pr_w2[j * 64 + i] * sh_z1[b2][i];
    sh_z2[b2][j] = acc > 0.0 ? acc : 0.0;
  }
  __syncthreads();
  if (tid < 16) {
    int b2 = tid >> 1, c = tid & 1;
    double acc = (double)pr_b3[c];
    for (int i = 0; i < 32; ++i) acc += (double)pr_w3[c * 32 + i] * sh_z2[b2][i];
    double fac = 1.0 / (1.0 + exp(-(double)iter_w_p[0] * iterv));
    sh_res[b2][c] = tanh(acc) * fac * 0.1;
  }
  __syncthreads();
  if (tid == 0) {
    double r0 = 0.0, r1 = 0.0;
    for (int q = 0; q < Bq; ++q) { r0 += sh_res[q][0]; r1 += sh_res[q][1]; }
    double na = fmin(fmax(alpha + r0 * alpha * (1.0 / Bq), 1e-6), 0.01);
    double nb = fmin(fmax(beta + r1 * beta * (1.0 / Bq), 1e-6), 0.1);
    double betathr = fmin(pow(10.0, iterv / 36.0 - 10.0), nb);
    sh_hdr[0] = na;
    sh_hdr[1] = 2.0 / na;       // coefA
    sh_hdr[2] = 2.0 / betathr;  // coefS
    sh_hdr[3] = 1.0 / na;       // inv_alpha
    hdr[0] = na;                // for final_kernel (identical across blocks)
    hdr[4] = 1.0 / na;
    out_scal[0] = (float)na;
    out_scal[1] = (float)nb;
  }
  __syncthreads();
  const float coefA = (float)sh_hdr[1];
  const float coefS = (float)sh_hdr[2];
  const double inva = sh_hdr[3];

  // ---- u scale for batch b (per-wave redundant, f64) ----
  double tv[NL];
  {
    double n0 = 0.0, n1 = 0.0;
#pragma unroll
    for (int e = 0; e < NL; ++e) {
      int gi = bb + lane * NL + e;
      tv[e] = (double)s[gi] - (double)sum_x[gi] - (double)sum_y[gi] -
              (double)lamuda[gi] * inva;
      ((e & 1) ? n1 : n0) += tv[e] * tv[e];
    }
    double nsq = wave_sum_d(n0 + n1);
    double nn = sqrt(nsq);
    double ee = sqrt((double)Nq * (double)var_p[0]);
    double scale = (nn > ee) ? ee / fmax(nn, 1e-30) : 1.0;
    double oms = 1.0 - scale;  // resid = tv*(1-scale) + xm*cos + ym*sin
#pragma unroll
    for (int e = 0; e < NL; ++e) tv[e] *= oms;
  }

  // ---- eIF cumtrapz phase + trig + per-wave system build ----
  const double dx = 1.0 / (double)fs_p[0];
  const double c0 = PI_D * dx;
  float df[NL], r[NL], x[NL];
  {
    double ev[NL], pl[NL];
#pragma unroll
    for (int e = 0; e < NL; ++e) ev[e] = (double)eIF[base + lane * NL + e];
    pl[0] = ev[0];
#pragma unroll
    for (int e = 1; e < NL; ++e) pl[e] = pl[e - 1] + ev[e];
    double offs = lane_excl_prefix_d(pl[NL - 1], lane);
    double y0 = __shfl(ev[0], 0, 64);
#pragma unroll
    for (int e = 0; e < NL; ++e) {
      int i = lane * NL + e;
      double ph = c0 * (2.0 * (offs + pl[e]) - ev[e] - y0);  // 2*pi*cumtrapz
      float sn, cs;
      fast_sincos_ph(ph, &sn, &cs);
      float xmv = xm[base + i], ymv = ym[base + i];
      double resid = tv[e] + (double)xmv * (double)cs + (double)ymv * (double)sn;
      if (wv == 0) {
        df[e] = cs * cs + 1e-6f;
        r[e] = (float)((double)cs * resid);
        x[e] = xmv;
      } else {
        df[e] = sn * sn + 1e-6f;
        r[e] = (float)((double)sn * resid);
        x[e] = ymv;
      }
    }
  }

  // ---- CG: wave0 solves X system, wave1 solves Y system (parallel) ----
  cg_wave_f<false>(coefA, df, r, x, lane);

  // publish xs/ys
  {
    float* dst = (wv == 0) ? sh_xs : sh_ys;
#pragma unroll
    for (int e = 0; e < NL; ++e) dst[e * 64 + lane] = x[e];
  }
  __syncthreads();

  // ---- deltaIF (both waves identically) ----
  {
    float xs[NL], ys[NL];
#pragma unroll
    for (int e = 0; e < NL; ++e) {
      xs[e] = sh_xs[e * 64 + lane];
      ys[e] = sh_ys[e * 64 + lane];
    }
    float invdx = (float)fs_p[0], inv2dx = 0.5f * invdx;
    float xl = __shfl_up(xs[NL - 1], 1, 64), xr = __shfl_down(xs[0], 1, 64);
    float yl = __shfl_up(ys[NL - 1], 1, 64), yr = __shfl_down(ys[0], 1, 64);
#pragma unroll
    for (int e = 0; e < NL; ++e) {
      int i = lane * NL + e;
      float xm1 = (e >= 1) ? xs[e - 1] : xl;
      float xp1 = (e <= NL - 2) ? xs[e + 1] : xr;
      float ym1 = (e >= 1) ? ys[e - 1] : yl;
      float yp1 = (e <= NL - 2) ? ys[e + 1] : yr;
      float xb, yb;
      if (i == 0) {
        xb = (xp1 - xs[e]) * invdx;
        yb = (yp1 - ys[e]) * invdx;
      } else if (i == Nq - 1) {
        xb = (xs[e] - xm1) * invdx;
        yb = (ys[e] - ym1) * invdx;
      } else {
        xb = (xp1 - xm1) * inv2dx;
        yb = (yp1 - ym1) * inv2dx;
      }
      float denom = xs[e] * xs[e] + ys[e] * ys[e] + 1e-12f;
      r[e] = (xs[e] * yb - ys[e] * xb) / (denom * (float)TWO_PI_D);
      x[e] = 0.0f;
    }
  }

  // ---- smooth CG (both waves redundantly; identical input -> identical) ----
  cg_wave_f<true>(coefS, nullptr, r, x, lane);

  // ---- epilogue: outputs + new-phase contributions ----
  bool active = mode_mask[row] != 0;
  double eifn[NL], pl[NL];
#pragma unroll
  for (int e = 0; e < NL; ++e) {
    int i = base + lane * NL + e;
    double eifv = (double)eIF[i];
    eifn[e] = active ? (eifv - 0.5 * (double)x[e]) : eifv;
  }
  if (wv == 0) {
#pragma unroll
    for (int e = 0; e < NL; ++e) {
      int i = base + lane * NL + e;
      out_eIF[i] = (float)eifn[e];
      out_xm[i] = active ? sh_xs[e * 64 + lane] : xm[i];
    }
  } else {
#pragma unroll
    for (int e = 0; e < NL; ++e) {
      int i = base + lane * NL + e;
      out_ym[i] = active ? sh_ys[e * 64 + lane] : ym[i];
    }
  }
  pl[0] = eifn[0];
#pragma unroll
  for (int e = 1; e < NL; ++e) pl[e] = pl[e - 1] + eifn[e];
  double offs = lane_excl_prefix_d(pl[NL - 1], lane);
  double y0 = __shfl(eifn[0], 0, 64);
#pragma unroll
  for (int e = 0; e < NL; ++e) {
    int i = base + lane * NL + e;
    double ph = c0 * (2.0 * (offs + pl[e]) - eifn[e] - y0);
    float sn, cs;
    fast_sincos_ph(ph, &sn, &cs);
    if (wv == 0)
      cx_w[i] = active ? sh_xs[e * 64 + lane] * cs : 0.0f;
    else
      cy_w[i] = active ? sh_ys[e * 64 + lane] * sn : 0.0f;
  }
}

// ---------------- final: bsx/bsy sums + u + new lamuda ----------------
__global__ __launch_bounds__(256) void final_kernel(
    const float* __restrict__ s, const float* __restrict__ sum_x,
    const float* __restrict__ sum_y, const float* __restrict__ lamuda,
    const float* __restrict__ var_p, const double* __restrict__ hdr,
    const float* __restrict__ cx_w, const float* __restrict__ cy_w,
    float* __restrict__ out_bsx, float* __restrict__ out_bsy,
    float* __restrict__ out_lam) {
  __shared__ double sh_red[4];
  __shared__ double sh_scale;
  int b = blockIdx.x;
  int bb = b * Nq;
  int tid = threadIdx.x;
  double na = hdr[0], inva = hdr[4];
  double t[8];
  double loc = 0.0;
#pragma unroll
  for (int e = 0; e < 8; ++e) {
    int gi = bb + tid + e * 256;
    t[e] = (double)s[gi] - (double)sum_x[gi] - (double)sum_y[gi] -
           (double)lamuda[gi] * inva;
    loc += t[e] * t[e];
  }
  double nsq = blk_reduce(loc, sh_red);
  if (tid == 0) {
    double n = sqrt(nsq);
    double ee = sqrt((double)Nq * (double)var_p[0]);
    sh_scale = (n > ee) ? ee / fmax(n, 1e-30) : 1.0;
  }
  __syncthreads();
  double scale = sh_scale;
#pragma unroll
  for (int e = 0; e < 8; ++e) {
    int i = tid + e * 256;
    int gi = bb + i;
    double bx = 0.0, by = 0.0;
#pragma unroll
    for (int k = 0; k < Kq; ++k) {
      bx += (double)cx_w[(b * Kq + k) * Nq + i];
      by += (double)cy_w[(b * Kq + k) * Nq + i];
    }
    double u = t[e] * scale;
    double nl = (double)lamuda[gi] + na * (u + bx + by - (double)s[gi]);
    out_bsx[gi] = (float)bx;
    out_bsy[gi] = (float)by;
    out_lam[gi] = (float)nl;
  }
}

// ---------------- launcher ----------------
extern "C" void kernel_launch(void* const* d_in, const int* in_sizes, int n_in,
                              void* d_out, int out_size, void* d_ws, size_t ws_size,
                              hipStream_t stream) {
  (void)in_sizes; (void)n_in; (void)out_size; (void)ws_size;
  const float* s = (const float*)d_in[0];
  const float* eIF = (const float*)d_in[1];
  const float* xm = (const float*)d_in[2];
  const float* ym = (const float*)d_in[3];
  const float* sum_x = (const float*)d_in[4];
  const float* sum_y = (const float*)d_in[5];
  const float* lamuda = (const float*)d_in[6];
  const float* init_freqs = (const float*)d_in[7];
  const int* mode_mask = (const int*)d_in[8];
  const float* alpha = (const float*)d_in[9];
  const float* beta = (const float*)d_in[10];
  const float* var = (const float*)d_in[11];
  const float* fs = (const float*)d_in[12];
  const int* iteration = (const int*)d_in[13];
  const float* fe_w1 = (const float*)d_in[14];
  const float* fe_b1 = (const float*)d_in[15];
  const float* fe_w2 = (const float*)d_in[16];
  const float* fe_b2 = (const float*)d_in[17];
  const float* pr_w1 = (const float*)d_in[18];
  const float* pr_b1 = (const float*)d_in[19];
  const float* pr_w2 = (const float*)d_in[20];
  const float* pr_b2 = (const float*)d_in[21];
  const float* pr_w3 = (const float*)d_in[22];
  const float* pr_b3 = (const float*)d_in[23];
  const float* iter_weight = (const float*)d_in[24];

  float* out = (float*)d_out;
  const int BN = Bq * Nq;      // 16384
  const int BKN = BKq * Nq;    // 65536
  float* out_eIF = out;
  float* out_xm = out + BKN;
  float* out_ym = out + 2 * BKN;
  float* out_bsx = out + 3 * BKN;
  float* out_bsy = out + 3 * BKN + BN;
  float* out_lam = out + 3 * BKN + 2 * BN;
  float* out_scal = out + 3 * BKN + 3 * BN;  // [new_alpha, new_beta]

  double* W = (double*)d_ws;
  double* hdr = W;                   // 16 doubles
  float* F = (float*)(W + 16);
  float* cx_w = F;                   // BKN floats
  float* cy_w = F + BKN;             // BKN floats

  row_kernel<<<BKq, 128, 0, stream>>>(
      s, eIF, xm, ym, sum_x, sum_y, lamuda, init_freqs, mode_mask, alpha, beta,
      var, fs, iteration, fe_w1, fe_b1, fe_w2, fe_b2, pr_w1, pr_b1, pr_w2,
      pr_b2, pr_w3, pr_b3, iter_weight, hdr, out_eIF, out_xm, out_ym, cx_w,
      cy_w, out_scal);
  final_kernel<<<Bq, 256, 0, stream>>>(s, sum_x, sum_y, lamuda, var, hdr, cx_w,
                                       cy_w, out_bsx, out_bsy, out_lam);
}